// Round 3
// baseline (689.448 us; speedup 1.0000x reference)
//
#include <hip/hip_runtime.h>
#include <hip/hip_bf16.h>

#define CHW4 16384   // one bg-group in float4 (16 ch * 64 * 64 / 4)
#define STRD 72      // dwords per staged row (18 float4 slots)

__device__ __forceinline__ float wred(float v){
#pragma unroll
  for (int o = 32; o; o >>= 1) v += __shfl_xor(v, o, 64);
  return v;
}
__device__ __forceinline__ float wred16(float v){
#pragma unroll
  for (int o = 8; o; o >>= 1) v += __shfl_xor(v, o, 64);
  return v;
}
__device__ __forceinline__ float bf2f(unsigned short u){
  return __uint_as_float(((unsigned)u) << 16);
}
__device__ __forceinline__ unsigned short f2b(float f){
  union { __hip_bfloat16 h; unsigned short u; } cv;
  cv.h = __float2bfloat16(f);
  return cv.u;
}

// One block per bg-group.
// Conv staging layout: logical float4-slot s (covering x cols [s*4-4, s*4)) of a
// row is stored at physical slot p = (s>>1) + 9*(s&1).  A lane (8 output px at
// w0=8c) needs logical slots 2c..2c+3 = physical {c, c+9, c+1, c+10}: each of
// the four ds_read_b128 then has octet lanes at 4-dword stride -> all 8 bank
// groups distinct -> conflict-free (was 2-way on every read before).
__global__ __launch_bounds__(1024, 4) void ema_fused(const float* __restrict__ x,
    const float* __restrict__ w1, const float* __restrict__ b1,
    const float* __restrict__ wh, const float* __restrict__ bh,
    const float* __restrict__ ww, const float* __restrict__ bw,
    const float* __restrict__ w3, const float* __restrict__ b3,
    const float* __restrict__ gnw, const float* __restrict__ gnb,
    float* __restrict__ out)
{
  // LDS: 131072 (E3s) + 8192 (rs/cs) + 1024 (v3p/z3p) + 23040 (scr) = 163328 B
  __shared__ __align__(16) unsigned short E3s[65536];  // exp(relu(conv3)) bf16 [co][h*64+w]
  __shared__ float rs_s[1024], cs_s[1024];             // pooled row/col sums [ci][h] / [ci][w]
  __shared__ float v3p[128], z3p[128];                 // [stripe][co]
  __shared__ __align__(16) float scr[5760];            // conv staging | ym/ahs/aws/smalls

  const int tid = threadIdx.x;
  const int bg  = blockIdx.x;
  const float4* x4 = (const float4*)x + (size_t)bg * CHW4;
  float4* o4 = (float4*)out + (size_t)bg * CHW4;

  const int lane = tid & 63;
  const int unit = __builtin_amdgcn_readfirstlane(tid >> 8);        // 0..3
  const int ut   = tid & 255;
  const int cog  = __builtin_amdgcn_readfirstlane((tid & 255) >> 6);
  const int co0  = cog * 4;
  const int cr   = lane >> 3;          // conv output row within stripe
  const int cc   = lane & 7;           // conv output col-chunk (8 px)
  float* in_u = scr + unit * 1440;     // 2ci x 10 rows x STRD

  // staging map (round-invariant): idx = c2*180 + rr*18 + p
  const int p0 = ut % 18, rr0 = (ut / 18) % 10, c20 = ut / 180;
  const int sl0 = (p0 <= 8) ? 2*p0 : 2*(p0-9)+1;
  const int ut1 = ut + 256;
  const int p1 = ut1 % 18, rr1 = (ut1 / 18) % 10, c21 = ut1 / 180;
  const int sl1 = (p1 <= 8) ? 2*p1 : 2*(p1-9)+1;
  const bool have1 = (ut < 104);

  // pooling map (reads staged tile each round)
  const int pc2  = ut >> 7;            // ci within pair (wave-pair uniform)
  const int prow = (ut >> 4) & 7;      // owned row 0..7
  const int wseg = ut & 15;            // 4-col segment
  const int sPP  = wseg + 1;
  const int pPP  = (sPP >> 1) + 9*(sPP & 1);

  cs_s[tid] = 0.f;                     // zero col-sum accumulators

  // ================= conv phase =================
  float acc[4][8];
#pragma unroll
  for (int i = 0; i < 4; ++i)
#pragma unroll
    for (int px = 0; px < 8; ++px) acc[i][px] = 0.f;

  float4 pa, pb;
  {  // prefetch round 0 (stripe unit*2, ci chunk 0)
    int hb = unit*16 - 1;
    pa = make_float4(0.f,0.f,0.f,0.f); pb = make_float4(0.f,0.f,0.f,0.f);
    int hh0 = hb + rr0;
    if (sl0 >= 1 && sl0 <= 16 && (unsigned)hh0 < 64u)
      pa = x4[c20*1024 + hh0*16 + (sl0-1)];
    if (have1){
      int hh1 = hb + rr1;
      if (sl1 >= 1 && sl1 <= 16 && (unsigned)hh1 < 64u)
        pb = x4[c21*1024 + hh1*16 + (sl1-1)];
    }
  }

#pragma unroll 1
  for (int round = 0; round < 16; ++round){
    __syncthreads();                       // prev round's LDS reads done
    *(float4*)&in_u[(c20*10 + rr0)*STRD + p0*4] = pa;
    if (have1) *(float4*)&in_u[(c21*10 + rr1)*STRD + p1*4] = pb;
    __syncthreads();                       // staged data visible
    if (round < 15){                       // issue next round's loads early
      int rn = round + 1;
      int sgn = unit*2 + (rn >> 3);
      int cbn = (rn & 7) * 2;
      int hb = sgn*8 - 1;
      pa = make_float4(0.f,0.f,0.f,0.f); pb = make_float4(0.f,0.f,0.f,0.f);
      int hh0 = hb + rr0;
      if (sl0 >= 1 && sl0 <= 16 && (unsigned)hh0 < 64u)
        pa = x4[(cbn + c20)*1024 + hh0*16 + (sl0-1)];
      if (have1){
        int hh1 = hb + rr1;
        if (sl1 >= 1 && sl1 <= 16 && (unsigned)hh1 < 64u)
          pb = x4[(cbn + c21)*1024 + hh1*16 + (sl1-1)];
      }
    }
    const int cb = (round & 7) * 2;
    const int sg = unit*2 + (round >> 3);
#pragma unroll
    for (int c2 = 0; c2 < 2; ++c2){
      const int ci = cb + c2;
      float wgt[4][9];
#pragma unroll
      for (int i = 0; i < 4; ++i)
#pragma unroll
        for (int t = 0; t < 9; ++t)
          wgt[i][t] = w3[((co0+i)*16 + ci)*9 + t];   // wave-uniform -> scalar loads
#pragma unroll
      for (int dy = 0; dy < 3; ++dy){
        const float* rowp = &in_u[(c2*10 + cr + dy)*STRD];
        float4 A0  = *(const float4*)(rowp + 4*cc);        // logical 2c
        float4 A1  = *(const float4*)(rowp + 4*(cc+9));    // logical 2c+1
        float4 A2v = *(const float4*)(rowp + 4*(cc+1));    // logical 2c+2
        float4 A3v = *(const float4*)(rowp + 4*(cc+10));   // logical 2c+3
        float v[16] = {A0.x,A0.y,A0.z,A0.w, A1.x,A1.y,A1.z,A1.w,
                       A2v.x,A2v.y,A2v.z,A2v.w, A3v.x,A3v.y,A3v.z,A3v.w};
#pragma unroll
        for (int dx = 0; dx < 3; ++dx)
#pragma unroll
          for (int px = 0; px < 8; ++px){
            float iv = v[px + dx + 3];
#pragma unroll
            for (int i = 0; i < 4; ++i)
              acc[i][px] = fmaf(wgt[i][dy*3+dx], iv, acc[i][px]);
          }
      }
    }
    // ---- pooled row/col sums from the staged tile (replaces pass-0 x sweep) ----
    {
      float4 pv = *(const float4*)&in_u[(pc2*10 + 1 + prow)*STRD + pPP*4];
      int ci = cb + pc2;
      float rsum = pv.x + pv.y + pv.z + pv.w;
      rsum = wred16(rsum);
      if ((lane & 15) == 0) rs_s[ci*64 + sg*8 + prow] = rsum;
      pv.x += __shfl_xor(pv.x,16); pv.x += __shfl_xor(pv.x,32);
      pv.y += __shfl_xor(pv.y,16); pv.y += __shfl_xor(pv.y,32);
      pv.z += __shfl_xor(pv.z,16); pv.z += __shfl_xor(pv.z,32);
      pv.w += __shfl_xor(pv.w,16); pv.w += __shfl_xor(pv.w,32);
      if (lane < 16){
        atomicAdd(&cs_s[ci*64 + wseg*4 + 0], pv.x);
        atomicAdd(&cs_s[ci*64 + wseg*4 + 1], pv.y);
        atomicAdd(&cs_s[ci*64 + wseg*4 + 2], pv.z);
        atomicAdd(&cs_s[ci*64 + wseg*4 + 3], pv.w);
      }
    }
    if ((round & 7) == 7){
      // stripe epilogue: relu/exp -> E3s (bf16), V3/Z3 stripe partials
      const int hh = sg*8 + cr;
#pragma unroll
      for (int i = 0; i < 4; ++i){
        float bias = b3[co0+i];
        union { unsigned short hb16[8]; uint4 u; } pk;
        float v3acc = 0.f, z3acc = 0.f;
#pragma unroll
        for (int px = 0; px < 8; ++px){
          float val = fmaxf(acc[i][px] + bias, 0.f);
          float e = __expf(val);
          v3acc += val; z3acc += e;
          pk.hb16[px] = f2b(e);
          acc[i][px] = 0.f;                 // reset for next stripe
        }
        *(uint4*)&E3s[(co0+i)*4096 + hh*64 + cc*8] = pk.u;
        float rv = wred(v3acc);
        float rz = wred(z3acc);
        if (lane == 0){
          v3p[sg*16 + co0 + i] = rv;
          z3p[sg*16 + co0 + i] = rz;
        }
      }
    }
  }

  // ================= pooled-attention + stats =================
  float* ym  = scr;            // [2048]
  float* ahs = scr + 2048;     // [1024]
  float* aws = scr + 3072;     // [1024]
  float* chpart = scr + 4096;  // [256]
  float* zpart  = scr + 4352;  // [256]
  float* red1   = scr + 4608;  // [16]
  float* red2   = scr + 4624;  // [16]
  float* murs   = scr + 4640;  // [2]
  float* sc_s   = scr + 4656;  // [16]
  float* of_s   = scr + 4672;  // [16]
  float* v2_s   = scr + 4688;  // [16]
  float* p2s    = scr + 4704;  // [16]
  float* p3s    = scr + 4720;  // [16]
  float* invS   = scr + 4736;  // [1]

  const int h   = tid >> 4;
  const int w4i = tid & 15;
  const int wv  = tid >> 6;

  __syncthreads();             // conv + pooling done; staging region reusable

  // y = relu(w1 @ [rowmean|colmean] + b1)
  for (int ol = tid; ol < 2048; ol += 1024){
    int o = ol >> 7, l = ol & 127;
    float a = b1[o];
#pragma unroll
    for (int i = 0; i < 16; ++i){
      float mv = (l < 64 ? rs_s[i*64 + l] : cs_s[i*64 + (l-64)]) * (1.f/64.f);
      a = fmaf(w1[o*16 + i], mv, a);
    }
    ym[o*128 + l] = fmaxf(a, 0.f);
  }
  __syncthreads();
  for (int ol = tid; ol < 2048; ol += 1024){
    int q = ol >> 10;
    int o = (ol >> 6) & 15;
    int p = ol & 63;
    const float* Wm = q ? ww : wh;
    float a = q ? bw[o] : bh[o];
#pragma unroll
    for (int i = 0; i < 16; ++i)
      a = fmaf(Wm[o*16 + i], ym[i*128 + q*64 + p], a);
    float sgm = 1.f / (1.f + __expf(-a));
    (q ? aws : ahs)[o*64 + p] = sgm;
  }
  __syncthreads();

  // ---- pass A: mu/var + per-channel sums ----
  const float4* aws4 = (const float4*)aws;
  float s1 = 0.f, s2 = 0.f;
#pragma unroll 8
  for (int k = 0; k < 16; ++k){
    float4 v = x4[k*1024 + tid];
    float ah = ahs[k*64 + h];
    float4 aw = aws4[k*16 + w4i];
    float4 x1;
    x1.x = v.x * ah * aw.x;
    x1.y = v.y * ah * aw.y;
    x1.z = v.z * ah * aw.z;
    x1.w = v.w * ah * aw.w;
    float csum = x1.x + x1.y + x1.z + x1.w;
    s1 += csum;
    s2 = fmaf(x1.x, x1.x, s2); s2 = fmaf(x1.y, x1.y, s2);
    s2 = fmaf(x1.z, x1.z, s2); s2 = fmaf(x1.w, x1.w, s2);
    float cw = wred(csum);
    if (lane == 0) chpart[k*16 + wv] = cw;
  }
  float r1 = wred(s1), r2 = wred(s2);
  if (lane == 0){ red1[wv] = r1; red2[wv] = r2; }
  __syncthreads();
  if (tid == 0){
    float S = 0.f, SS = 0.f;
#pragma unroll
    for (int i = 0; i < 16; ++i){ S += red1[i]; SS += red2[i]; }
    float mu  = S * (1.f/65536.f);
    float var = SS * (1.f/65536.f) - mu*mu;
    murs[0] = mu; murs[1] = rsqrtf(var + 1e-5f);
  }
  __syncthreads();
  if (tid < 16){
    float ch = 0.f;
#pragma unroll
    for (int m = 0; m < 16; ++m) ch += chpart[tid*16 + m];
    float mu = murs[0], rstd = murs[1];
    float g = gnw[tid], b = gnb[tid];
    float sc = rstd * g;
    sc_s[tid] = sc; of_s[tid] = b - mu*sc;
    v2_s[tid] = (ch * (1.f/4096.f) - mu) * sc + b;   // V2
  }
  __syncthreads();

  // ---- pass B: Z2 per channel; keep exp(x2) bf16-packed in regs ----
  unsigned e2a[16], e2b[16];
#pragma unroll
  for (int k = 0; k < 16; ++k){
    float4 v = x4[k*1024 + tid];
    float ah = ahs[k*64 + h];
    float4 aw = aws4[k*16 + w4i];
    float sc = sc_s[k], of = of_s[k];
    float ex = __expf(fmaf(v.x * ah * aw.x, sc, of));
    float ey = __expf(fmaf(v.y * ah * aw.y, sc, of));
    float ez = __expf(fmaf(v.z * ah * aw.z, sc, of));
    float ew = __expf(fmaf(v.w * ah * aw.w, sc, of));
    float z = ex + ey + ez + ew;
    e2a[k] = (unsigned)f2b(ex) | ((unsigned)f2b(ey) << 16);
    e2b[k] = (unsigned)f2b(ez) | ((unsigned)f2b(ew) << 16);
    float zw = wred(z);
    if (lane == 0) zpart[k*16 + wv] = zw;
  }
  __syncthreads();
  if (tid < 16){
    float z2 = 0.f;
#pragma unroll
    for (int m = 0; m < 16; ++m) z2 += zpart[tid*16 + m];
    float v3 = 0.f, z3 = 0.f;
#pragma unroll
    for (int ss = 0; ss < 8; ++ss){
      v3 += v3p[ss*16 + tid];
      z3 += z3p[ss*16 + tid];
    }
    p2s[tid] = v3 * (1.f/4096.f) / z2;   // multiplies exp(x2):  V3 * A2
    p3s[tid] = v2_s[tid] / z3;           // multiplies exp(x3):  V2 * A3
  }
  __syncthreads();

  // ---- pass C: t from register exp(x2) + LDS E3 (no x re-read) ----
  float4 tacc = make_float4(0.f,0.f,0.f,0.f);
#pragma unroll
  for (int k = 0; k < 16; ++k){
    ushort4 eu = *(const ushort4*)&E3s[k*4096 + tid*4];
    float p2 = p2s[k], p3 = p3s[k];
    tacc.x += bf2f((unsigned short)(e2a[k] & 0xffffu))*p2 + bf2f(eu.x)*p3;
    tacc.y += bf2f((unsigned short)(e2a[k] >> 16))   *p2 + bf2f(eu.y)*p3;
    tacc.z += bf2f((unsigned short)(e2b[k] & 0xffffu))*p2 + bf2f(eu.z)*p3;
    tacc.w += bf2f((unsigned short)(e2b[k] >> 16))   *p2 + bf2f(eu.w)*p3;
  }
  float4 e;
  e.x = __expf(tacc.x); e.y = __expf(tacc.y);
  e.z = __expf(tacc.z); e.w = __expf(tacc.w);
  float es = e.x + e.y + e.z + e.w;
  float rr = wred(es);
  if (lane == 0) red1[wv] = rr;
  __syncthreads();
  if (tid == 0){
    float S = 0.f;
#pragma unroll
    for (int i = 0; i < 16; ++i) S += red1[i];
    invS[0] = 1.f / S;
  }
  __syncthreads();
  float iS = invS[0];
  float4 ei = make_float4(e.x*iS, e.y*iS, e.z*iS, e.w*iS);

  // ---- pass D: out = x * s ----
#pragma unroll 8
  for (int k = 0; k < 16; ++k){
    float4 v = x4[k*1024 + tid];
    float4 ov;
    ov.x = v.x * ei.x; ov.y = v.y * ei.y;
    ov.z = v.z * ei.z; ov.w = v.w * ei.w;
    o4[k*1024 + tid] = ov;
  }
}

extern "C" void kernel_launch(void* const* d_in, const int* in_sizes, int n_in,
                              void* d_out, int out_size, void* d_ws, size_t ws_size,
                              hipStream_t stream)
{
  const float* x   = (const float*)d_in[0];
  const float* w1  = (const float*)d_in[1];
  const float* b1  = (const float*)d_in[2];
  const float* wh  = (const float*)d_in[3];
  const float* bh  = (const float*)d_in[4];
  const float* ww  = (const float*)d_in[5];
  const float* bw  = (const float*)d_in[6];
  const float* w3  = (const float*)d_in[7];
  const float* b3  = (const float*)d_in[8];
  const float* gnw = (const float*)d_in[9];
  const float* gnb = (const float*)d_in[10];
  float* out = (float*)d_out;
  (void)d_ws; (void)ws_size; (void)n_in; (void)in_sizes; (void)out_size;

  ema_fused<<<dim3(512), 1024, 0, stream>>>(x, w1, b1, wh, bh, ww, bw,
                                            w3, b3, gnw, gnb, out);
}

// Round 4
// 452.368 us; speedup vs baseline: 1.5241x; 1.5241x over previous
//
#include <hip/hip_runtime.h>
#include <hip/hip_bf16.h>

#define CHW  65536   // 16 ch * 64 * 64 per bg-group
#define CHW4 16384   // in float4
#define KSTR 72      // staged row stride in dwords (18 float4 slots, permuted)

__device__ __forceinline__ float wred(float v){
#pragma unroll
  for (int o = 32; o; o >>= 1) v += __shfl_xor(v, o, 64);
  return v;
}
__device__ __forceinline__ float wred16(float v){
#pragma unroll
  for (int o = 8; o; o >>= 1) v += __shfl_xor(v, o, 64);
  return v;
}
__device__ __forceinline__ float bf2f(unsigned short u){
  return __uint_as_float(((unsigned)u) << 16);
}
__device__ __forceinline__ unsigned short f2b(float f){
  union { __hip_bfloat16 h; unsigned short u; } cv;
  cv.h = __float2bfloat16(f);
  return cv.u;
}

// ---------------- K3: 3x3 grouped conv -> E3=exp(relu(x3)) (bf16), V3/Z3 partials,
// plus pooled row/col-sum partials computed from the staged LDS tiles. ----------
// Staging permutation: logical float4-slot s of a row at physical p=(s>>1)+9*(s&1).
// A lane's four ds_read_b128 (logical slots 2c..2c+3) land at physical
// {c, c+9, c+1, c+10}: each read's 8 octet lanes tile all 32 banks exactly once.
__global__ __launch_bounds__(256, 6) void k3_conv(const float* __restrict__ x,
    const float* __restrict__ w3, const float* __restrict__ b3,
    __hip_bfloat16* __restrict__ E3,
    float* __restrict__ V3part, float* __restrict__ Z3part,
    float* __restrict__ rs_g, float* __restrict__ csp_g)
{
  __shared__ __align__(16) float in_s[8*10*KSTR];   // 23040 B -> 7 blocks/CU
  int tid = threadIdx.x;
  int st  = blockIdx.x;      // stripe 0..7
  int bg  = blockIdx.y;
  size_t base  = (size_t)bg * CHW;
  const float4* x4 = (const float4*)x + (size_t)bg * CHW4;
  int lane = tid & 63;
  int cog = __builtin_amdgcn_readfirstlane(tid >> 6);  // wave-uniform co group
  int co0 = cog * 4;
  int r  = lane >> 3;          // output row within stripe
  int cc = lane & 7;           // 8-px col chunk
  float acc[4][8];
#pragma unroll
  for (int i = 0; i < 4; ++i)
#pragma unroll
    for (int px = 0; px < 8; ++px) acc[i][px] = 0.f;

#pragma unroll 1
  for (int half = 0; half < 2; ++half){
    __syncthreads();
    // stage 8 ci x 10 rows x 18 slots (permuted), cols -4..67 zero-padded
    for (int idx = tid; idx < 1440; idx += 256){
      int p   = idx % 18;
      int rr  = (idx / 18) % 10;
      int ci8 = idx / 180;
      int sl  = (p <= 8) ? 2*p : 2*(p-9)+1;     // logical slot
      int hh  = st*8 - 1 + rr;
      float4 v = make_float4(0.f, 0.f, 0.f, 0.f);
      if (sl >= 1 && sl <= 16 && (unsigned)hh < 64u)
        v = x4[(half*8 + ci8)*1024 + hh*16 + (sl-1)];
      *(float4*)&in_s[(ci8*10 + rr)*KSTR + p*4] = v;
    }
    __syncthreads();

    // ---- pooled row sums from staged tiles (owned rows only) ----
    {
      int task = tid >> 2, sub = tid & 3;       // 64 tasks x 4 threads
      int pci = task >> 3, prow = task & 7;
      const float* rowp = &in_s[(pci*10 + 1 + prow)*KSTR];
      float4 a  = *(const float4*)(rowp + 4*(2*sub+9));    // slot 4sub+1
      float4 b  = *(const float4*)(rowp + 4*(2*sub+1));    // slot 4sub+2
      float4 cf = *(const float4*)(rowp + 4*(2*sub+10));   // slot 4sub+3
      float4 d  = *(const float4*)(rowp + 4*(2*sub+2));    // slot 4sub+4
      float sm = a.x+a.y+a.z+a.w + b.x+b.y+b.z+b.w
               + cf.x+cf.y+cf.z+cf.w + d.x+d.y+d.z+d.w;
      sm += __shfl_xor(sm, 1, 64);
      sm += __shfl_xor(sm, 2, 64);
      if (sub == 0)
        rs_g[(size_t)bg*1024 + (half*8 + pci)*64 + st*8 + prow] = sm;
    }
    // ---- pooled col-sum partials (this stripe's 8 rows) ----
    {
      int pci = tid >> 5;
      int c0  = (tid & 31) * 2;
#pragma unroll
      for (int e = 0; e < 2; ++e){
        int c  = c0 + e;
        int sl = (c >> 2) + 1;
        int pp = (sl >> 1) + 9*(sl & 1);
        int dd = pp*4 + (c & 3);
        float a2 = 0.f;
#pragma unroll
        for (int rr2 = 0; rr2 < 8; ++rr2)
          a2 += in_s[(pci*10 + 1 + rr2)*KSTR + dd];
        csp_g[((size_t)(bg*8 + st)*16 + half*8 + pci)*64 + c] = a2;
      }
    }

#pragma unroll 1
    for (int ci8 = 0; ci8 < 8; ++ci8){
      int ci = half*8 + ci8;
      float wgt[4][9];
#pragma unroll
      for (int i = 0; i < 4; ++i)
#pragma unroll
        for (int t = 0; t < 9; ++t)
          wgt[i][t] = w3[((co0+i)*16 + ci)*9 + t];   // wave-uniform -> scalar loads
#pragma unroll
      for (int dy = 0; dy < 3; ++dy){
        const float* rowp = &in_s[(ci8*10 + r + dy)*KSTR];
        float4 A0  = *(const float4*)(rowp + 4*cc);        // logical slot 2c
        float4 A1  = *(const float4*)(rowp + 4*(cc+9));    // logical slot 2c+1
        float4 A2v = *(const float4*)(rowp + 4*(cc+1));    // logical slot 2c+2
        float4 A3v = *(const float4*)(rowp + 4*(cc+10));   // logical slot 2c+3
        float v[16] = {A0.x,A0.y,A0.z,A0.w, A1.x,A1.y,A1.z,A1.w,
                       A2v.x,A2v.y,A2v.z,A2v.w, A3v.x,A3v.y,A3v.z,A3v.w};
#pragma unroll
        for (int dx = 0; dx < 3; ++dx){
#pragma unroll
          for (int px = 0; px < 8; ++px){
            float iv = v[px + dx + 3];
#pragma unroll
            for (int i = 0; i < 4; ++i)
              acc[i][px] = fmaf(wgt[i][dy*3+dx], iv, acc[i][px]);
          }
        }
      }
    }
  }
  int hh = st*8 + r;
#pragma unroll
  for (int i = 0; i < 4; ++i){
    float bias = b3[co0+i];
    union { unsigned short hb[8]; uint4 u; } pk;
    float v3acc = 0.f, z3acc = 0.f;
#pragma unroll
    for (int px = 0; px < 8; ++px){
      float val = fmaxf(acc[i][px] + bias, 0.f);   // x3
      float e = __expf(val);
      v3acc += val;
      z3acc += e;
      pk.hb[px] = f2b(e);
    }
    *(uint4*)&E3[base + (size_t)(co0+i)*4096 + hh*64 + cc*8] = pk.u;
    float rv = wred(v3acc);
    float rz = wred(z3acc);
    if (lane == 0){
      V3part[((size_t)bg*8 + st)*16 + co0 + i] = rv;
      Z3part[((size_t)bg*8 + st)*16 + co0 + i] = rz;
    }
  }
}

// ---------------- MEGA: attention maps + stats + t softmax + out ------------
// pass0 x-sweep replaced by reading k3's pooled partials; passC reads no x
// (exp(x2) carried bf16-packed in registers from passB).
__global__ __launch_bounds__(1024, 8) void mega(const float* __restrict__ x,
    const float* __restrict__ w1, const float* __restrict__ b1,
    const float* __restrict__ wh, const float* __restrict__ bh,
    const float* __restrict__ ww, const float* __restrict__ bw,
    const float* __restrict__ gnw, const float* __restrict__ gnb,
    const float* __restrict__ V3part, const float* __restrict__ Z3part,
    const float* __restrict__ rs_g, const float* __restrict__ csp_g,
    const __hip_bfloat16* __restrict__ E3,
    float* __restrict__ out)
{
  __shared__ float rs[1024];                 // rowsum[ch*64+h]
  __shared__ float cs[1024];                 // colsum[ch*64+w]
  __shared__ float ym[2048];
  __shared__ __align__(16) float ahs[1024], aws[1024];
  __shared__ float chpart[256], zpart[256];
  __shared__ float red1[16], red2[16];
  __shared__ float murs[2];
  __shared__ float sc_s[16], of_s[16], v2_s[16], p2s[16], p3s[16];
  __shared__ float invS_s;

  int tid = threadIdx.x, bg = blockIdx.x;
  const float4* x4 = (const float4*)x + (size_t)bg * CHW4;
  const ushort4* E34 = (const ushort4*)E3 + (size_t)bg * CHW4;
  float4* o4 = (float4*)out + (size_t)bg * CHW4;
  int h = tid >> 4, w4 = tid & 15, lane = tid & 63, wv = tid >> 6;

  // ---- pass 0': pooled sums from k3 partials (no x sweep) ----
  rs[tid] = rs_g[(size_t)bg*1024 + tid];
  {
    const float* cp = csp_g + (size_t)bg*8192;
    float csum = 0.f;
#pragma unroll
    for (int ss = 0; ss < 8; ++ss) csum += cp[ss*1024 + tid];
    cs[tid] = csum;
  }
  __syncthreads();
  // y = relu(w1 @ [rowmean|colmean] + b1)
  for (int ol = tid; ol < 2048; ol += 1024){
    int o = ol >> 7, l = ol & 127;
    float acc = b1[o];
#pragma unroll
    for (int i = 0; i < 16; ++i){
      float mv = (l < 64 ? rs[i*64 + l] : cs[i*64 + (l-64)]) * (1.f/64.f);
      acc = fmaf(w1[o*16 + i], mv, acc);
    }
    ym[o*128 + l] = fmaxf(acc, 0.f);
  }
  __syncthreads();
  for (int ol = tid; ol < 2048; ol += 1024){
    int q = ol >> 10;             // 0 -> a_h, 1 -> a_w
    int o = (ol >> 6) & 15;
    int p = ol & 63;
    const float* Wm = q ? ww : wh;
    float acc = q ? bw[o] : bh[o];
#pragma unroll
    for (int i = 0; i < 16; ++i)
      acc = fmaf(Wm[o*16 + i], ym[i*128 + q*64 + p], acc);
    float sg = 1.f / (1.f + __expf(-acc));
    (q ? aws : ahs)[o*64 + p] = sg;
  }
  __syncthreads();

  // ---- pass A: mu/var + per-channel sums ----
  const float4* aws4 = (const float4*)aws;
  float s1 = 0.f, s2 = 0.f;
#pragma unroll 4
  for (int k = 0; k < 16; ++k){
    float4 v = x4[k*1024 + tid];
    float ah = ahs[k*64 + h];
    float4 aw = aws4[k*16 + w4];
    float4 x1;
    x1.x = v.x * ah * aw.x;
    x1.y = v.y * ah * aw.y;
    x1.z = v.z * ah * aw.z;
    x1.w = v.w * ah * aw.w;
    float csum = x1.x + x1.y + x1.z + x1.w;
    s1 += csum;
    s2 = fmaf(x1.x, x1.x, s2); s2 = fmaf(x1.y, x1.y, s2);
    s2 = fmaf(x1.z, x1.z, s2); s2 = fmaf(x1.w, x1.w, s2);
    float cw = wred(csum);
    if (lane == 0) chpart[k*16 + wv] = cw;
  }
  float r1 = wred(s1), r2 = wred(s2);
  if (lane == 0){ red1[wv] = r1; red2[wv] = r2; }
  __syncthreads();
  if (tid == 0){
    float S = 0.f, SS = 0.f;
#pragma unroll
    for (int i = 0; i < 16; ++i){ S += red1[i]; SS += red2[i]; }
    float mu = S * (1.f/65536.f);
    float var = SS * (1.f/65536.f) - mu*mu;
    murs[0] = mu; murs[1] = rsqrtf(var + 1e-5f);
  }
  __syncthreads();
  if (tid < 16){
    float ch = 0.f;
#pragma unroll
    for (int m = 0; m < 16; ++m) ch += chpart[tid*16 + m];
    float mu = murs[0], rstd = murs[1];
    float g = gnw[tid], b = gnb[tid];
    float sc = rstd * g;
    sc_s[tid] = sc; of_s[tid] = b - mu*sc;
    v2_s[tid] = (ch * (1.f/4096.f) - mu) * sc + b;   // V2
  }
  __syncthreads();

  // ---- pass B: Z2 per channel; keep exp(x2) bf16-packed in regs ----
  unsigned e2a[16], e2b[16];
#pragma unroll 2
  for (int k = 0; k < 16; ++k){
    float4 v = x4[k*1024 + tid];
    float ah = ahs[k*64 + h];
    float4 aw = aws4[k*16 + w4];
    float sc = sc_s[k], of = of_s[k];
    float ex = __expf(fmaf(v.x * ah * aw.x, sc, of));
    float ey = __expf(fmaf(v.y * ah * aw.y, sc, of));
    float ez = __expf(fmaf(v.z * ah * aw.z, sc, of));
    float ew = __expf(fmaf(v.w * ah * aw.w, sc, of));
    float z = ex + ey + ez + ew;
    e2a[k] = (unsigned)f2b(ex) | ((unsigned)f2b(ey) << 16);
    e2b[k] = (unsigned)f2b(ez) | ((unsigned)f2b(ew) << 16);
    float zw = wred(z);
    if (lane == 0) zpart[k*16 + wv] = zw;
  }
  __syncthreads();
  if (tid < 16){
    float z2 = 0.f;
#pragma unroll
    for (int m = 0; m < 16; ++m) z2 += zpart[tid*16 + m];
    float v3 = 0.f, z3 = 0.f;
#pragma unroll
    for (int ss = 0; ss < 8; ++ss){
      v3 += V3part[((size_t)bg*8 + ss)*16 + tid];
      z3 += Z3part[((size_t)bg*8 + ss)*16 + tid];
    }
    p2s[tid] = v3 * (1.f/4096.f) / z2;   // multiplies exp(x2):  V3 * A2
    p3s[tid] = v2_s[tid] / z3;           // multiplies exp(x3):  V2 * A3
  }
  __syncthreads();

  // ---- pass C: t from register exp(x2) + global E3 (no x re-read) ----
  float4 tacc = make_float4(0.f,0.f,0.f,0.f);
#pragma unroll 4
  for (int k = 0; k < 16; ++k){
    ushort4 eu = E34[k*1024 + tid];
    float p2 = p2s[k], p3 = p3s[k];
    tacc.x += bf2f((unsigned short)(e2a[k] & 0xffffu))*p2 + bf2f(eu.x)*p3;
    tacc.y += bf2f((unsigned short)(e2a[k] >> 16))   *p2 + bf2f(eu.y)*p3;
    tacc.z += bf2f((unsigned short)(e2b[k] & 0xffffu))*p2 + bf2f(eu.z)*p3;
    tacc.w += bf2f((unsigned short)(e2b[k] >> 16))   *p2 + bf2f(eu.w)*p3;
  }
  float4 e;
  e.x = __expf(tacc.x); e.y = __expf(tacc.y);
  e.z = __expf(tacc.z); e.w = __expf(tacc.w);
  float es = e.x + e.y + e.z + e.w;
  float rr = wred(es);
  if (lane == 0) red1[wv] = rr;
  __syncthreads();
  if (tid == 0){
    float S = 0.f;
#pragma unroll
    for (int i = 0; i < 16; ++i) S += red1[i];
    invS_s = 1.f / S;
  }
  __syncthreads();
  float iS = invS_s;
  float4 ei = make_float4(e.x*iS, e.y*iS, e.z*iS, e.w*iS);

  // ---- pass D: out = x * s ----
#pragma unroll 4
  for (int k = 0; k < 16; ++k){
    float4 v = x4[k*1024 + tid];
    float4 ov;
    ov.x = v.x * ei.x; ov.y = v.y * ei.y;
    ov.z = v.z * ei.z; ov.w = v.w * ei.w;
    o4[k*1024 + tid] = ov;
  }
}

extern "C" void kernel_launch(void* const* d_in, const int* in_sizes, int n_in,
                              void* d_out, int out_size, void* d_ws, size_t ws_size,
                              hipStream_t stream)
{
  const float* x   = (const float*)d_in[0];
  const float* w1  = (const float*)d_in[1];
  const float* b1  = (const float*)d_in[2];
  const float* wh  = (const float*)d_in[3];
  const float* bh  = (const float*)d_in[4];
  const float* ww  = (const float*)d_in[5];
  const float* bw  = (const float*)d_in[6];
  const float* w3  = (const float*)d_in[7];
  const float* b3  = (const float*)d_in[8];
  const float* gnw = (const float*)d_in[9];
  const float* gnb = (const float*)d_in[10];
  float* out = (float*)d_out;

  float* V3part = (float*)d_ws;                        // 65536 floats
  float* Z3part = V3part + 65536;                      // 65536 floats
  float* rs_g   = Z3part + 65536;                      // 512*16*64   = 524288 floats
  float* csp_g  = rs_g + 524288;                       // 512*8*16*64 = 4194304 floats
  __hip_bfloat16* E3 = (__hip_bfloat16*)(csp_g + 4194304);  // 33554432 bf16 (64 MB)
  (void)ws_size; (void)n_in; (void)in_sizes; (void)out_size;

  k3_conv<<<dim3(8, 512), 256, 0, stream>>>(x, w3, b3, E3, V3part, Z3part,
                                            rs_g, csp_g);
  mega   <<<512, 1024, 0, stream>>>(x, w1, b1, wh, bh, ww, bw, gnw, gnb,
                                    V3part, Z3part, rs_g, csp_g, E3, out);
}

// Round 5
// 446.154 us; speedup vs baseline: 1.5453x; 1.0139x over previous
//
#include <hip/hip_runtime.h>
#include <hip/hip_bf16.h>

#define CHW  65536   // 16 ch * 64 * 64 per bg-group
#define CHW4 16384   // in float4
#define KSTR 76      // staged row stride in dwords = 19 16B-slots (ODD -> rows
                     // hit distinct slot-classes mod 8 for stride-8 lane groups)

__device__ __forceinline__ float wred(float v){
#pragma unroll
  for (int o = 32; o; o >>= 1) v += __shfl_xor(v, o, 64);
  return v;
}
__device__ __forceinline__ float wred16(float v){
#pragma unroll
  for (int o = 8; o; o >>= 1) v += __shfl_xor(v, o, 64);
  return v;
}
__device__ __forceinline__ float bf2f(unsigned short u){
  return __uint_as_float(((unsigned)u) << 16);
}
__device__ __forceinline__ unsigned short f2b(float f){
  union { __hip_bfloat16 h; unsigned short u; } cv;
  cv.h = __float2bfloat16(f);
  return cv.u;
}

// ---------------- K3: 3x3 grouped conv -> E3=exp(relu(x3)) (bf16), V3/Z3 partials,
// plus pooled row/col-sum partials computed from the staged LDS tiles. ----------
// Staging permutation: logical float4-slot s of a row at physical p=(s>>1)+9*(s&1)
// (consecutive lanes -> consecutive physical slots on each of the 4 reads).
// Row stride 19 slots (odd): stride-8 lane groups (same cc, rows 0..7) see slot
// 19r+cc -> 3r mod 8 = permutation -> distinct. Both lane-grouping models clean.
__global__ __launch_bounds__(256, 6) void k3_conv(const float* __restrict__ x,
    const float* __restrict__ w3, const float* __restrict__ b3,
    __hip_bfloat16* __restrict__ E3,
    float* __restrict__ V3part, float* __restrict__ Z3part,
    float* __restrict__ rs_g, float* __restrict__ csp_g)
{
  __shared__ __align__(16) float in_s[8*10*KSTR];   // 24320 B -> 6 blocks/CU
  int tid = threadIdx.x;
  int st  = blockIdx.x;      // stripe 0..7
  int bg  = blockIdx.y;
  size_t base  = (size_t)bg * CHW;
  const float4* x4 = (const float4*)x + (size_t)bg * CHW4;
  int lane = tid & 63;
  int cog = __builtin_amdgcn_readfirstlane(tid >> 6);  // wave-uniform co group
  int co0 = cog * 4;
  int r  = lane >> 3;          // output row within stripe
  int cc = lane & 7;           // 8-px col chunk
  float acc[4][8];
#pragma unroll
  for (int i = 0; i < 4; ++i)
#pragma unroll
    for (int px = 0; px < 8; ++px) acc[i][px] = 0.f;

#pragma unroll 1
  for (int half = 0; half < 2; ++half){
    __syncthreads();
    // stage 8 ci x 10 rows x 18 slots (permuted), cols -4..67 zero-padded
    for (int idx = tid; idx < 1440; idx += 256){
      int p   = idx % 18;
      int rr  = (idx / 18) % 10;
      int ci8 = idx / 180;
      int sl  = (p <= 8) ? 2*p : 2*(p-9)+1;     // logical slot
      int hh  = st*8 - 1 + rr;
      float4 v = make_float4(0.f, 0.f, 0.f, 0.f);
      if (sl >= 1 && sl <= 16 && (unsigned)hh < 64u)
        v = x4[(half*8 + ci8)*1024 + hh*16 + (sl-1)];
      *(float4*)&in_s[(ci8*10 + rr)*KSTR + p*4] = v;
    }
    __syncthreads();

    // ---- pooled row sums from staged tiles (owned rows only) ----
    {
      int task = tid >> 2, sub = tid & 3;       // 64 tasks x 4 threads
      int pci = task >> 3, prow = task & 7;
      const float* rowp = &in_s[(pci*10 + 1 + prow)*KSTR];
      float4 a  = *(const float4*)(rowp + 4*(2*sub+9));    // slot 4sub+1
      float4 b  = *(const float4*)(rowp + 4*(2*sub+1));    // slot 4sub+2
      float4 cf = *(const float4*)(rowp + 4*(2*sub+10));   // slot 4sub+3
      float4 d  = *(const float4*)(rowp + 4*(2*sub+2));    // slot 4sub+4
      float sm = a.x+a.y+a.z+a.w + b.x+b.y+b.z+b.w
               + cf.x+cf.y+cf.z+cf.w + d.x+d.y+d.z+d.w;
      sm += __shfl_xor(sm, 1, 64);
      sm += __shfl_xor(sm, 2, 64);
      if (sub == 0)
        rs_g[(size_t)bg*1024 + (half*8 + pci)*64 + st*8 + prow] = sm;
    }
    // ---- pooled col-sum partials (this stripe's 8 rows) ----
    {
      int pci = tid >> 5;
      int c0  = (tid & 31) * 2;
#pragma unroll
      for (int e = 0; e < 2; ++e){
        int c  = c0 + e;
        int sl = (c >> 2) + 1;
        int pp = (sl >> 1) + 9*(sl & 1);
        int dd = pp*4 + (c & 3);
        float a2 = 0.f;
#pragma unroll
        for (int rr2 = 0; rr2 < 8; ++rr2)
          a2 += in_s[(pci*10 + 1 + rr2)*KSTR + dd];
        csp_g[((size_t)(bg*8 + st)*16 + half*8 + pci)*64 + c] = a2;
      }
    }

#pragma unroll 1
    for (int ci8 = 0; ci8 < 8; ++ci8){
      int ci = half*8 + ci8;
      float wgt[4][9];
#pragma unroll
      for (int i = 0; i < 4; ++i)
#pragma unroll
        for (int t = 0; t < 9; ++t)
          wgt[i][t] = w3[((co0+i)*16 + ci)*9 + t];   // wave-uniform -> scalar loads
#pragma unroll
      for (int dy = 0; dy < 3; ++dy){
        const float* rowp = &in_s[(ci8*10 + r + dy)*KSTR];
        float4 A0  = *(const float4*)(rowp + 4*cc);        // logical slot 2c
        float4 A1  = *(const float4*)(rowp + 4*(cc+9));    // logical slot 2c+1
        float4 A2v = *(const float4*)(rowp + 4*(cc+1));    // logical slot 2c+2
        float4 A3v = *(const float4*)(rowp + 4*(cc+10));   // logical slot 2c+3
        float v[16] = {A0.x,A0.y,A0.z,A0.w, A1.x,A1.y,A1.z,A1.w,
                       A2v.x,A2v.y,A2v.z,A2v.w, A3v.x,A3v.y,A3v.z,A3v.w};
#pragma unroll
        for (int dx = 0; dx < 3; ++dx){
#pragma unroll
          for (int px = 0; px < 8; ++px){
            float iv = v[px + dx + 3];
#pragma unroll
            for (int i = 0; i < 4; ++i)
              acc[i][px] = fmaf(wgt[i][dy*3+dx], iv, acc[i][px]);
          }
        }
      }
    }
  }
  int hh = st*8 + r;
#pragma unroll
  for (int i = 0; i < 4; ++i){
    float bias = b3[co0+i];
    union { unsigned short hb[8]; uint4 u; } pk;
    float v3acc = 0.f, z3acc = 0.f;
#pragma unroll
    for (int px = 0; px < 8; ++px){
      float val = fmaxf(acc[i][px] + bias, 0.f);   // x3
      float e = __expf(val);
      v3acc += val;
      z3acc += e;
      pk.hb[px] = f2b(e);
    }
    *(uint4*)&E3[base + (size_t)(co0+i)*4096 + hh*64 + cc*8] = pk.u;
    float rv = wred(v3acc);
    float rz = wred(z3acc);
    if (lane == 0){
      V3part[((size_t)bg*8 + st)*16 + co0 + i] = rv;
      Z3part[((size_t)bg*8 + st)*16 + co0 + i] = rz;
    }
  }
}

// ---------------- MEGA: attention maps + stats + t softmax + out ------------
// pass0 x-sweep replaced by reading k3's pooled partials; passC reads no x
// (exp(x2) carried bf16-packed in registers from passB).
__global__ __launch_bounds__(1024, 8) void mega(const float* __restrict__ x,
    const float* __restrict__ w1, const float* __restrict__ b1,
    const float* __restrict__ wh, const float* __restrict__ bh,
    const float* __restrict__ ww, const float* __restrict__ bw,
    const float* __restrict__ gnw, const float* __restrict__ gnb,
    const float* __restrict__ V3part, const float* __restrict__ Z3part,
    const float* __restrict__ rs_g, const float* __restrict__ csp_g,
    const __hip_bfloat16* __restrict__ E3,
    float* __restrict__ out)
{
  __shared__ float rs[1024];                 // rowsum[ch*64+h]
  __shared__ float cs[1024];                 // colsum[ch*64+w]
  __shared__ float ym[2048];
  __shared__ __align__(16) float ahs[1024], aws[1024];
  __shared__ float chpart[256], zpart[256];
  __shared__ float red1[16], red2[16];
  __shared__ float murs[2];
  __shared__ float sc_s[16], of_s[16], v2_s[16], p2s[16], p3s[16];
  __shared__ float invS_s;

  int tid = threadIdx.x, bg = blockIdx.x;
  const float4* x4 = (const float4*)x + (size_t)bg * CHW4;
  const ushort4* E34 = (const ushort4*)E3 + (size_t)bg * CHW4;
  float4* o4 = (float4*)out + (size_t)bg * CHW4;
  int h = tid >> 4, w4 = tid & 15, lane = tid & 63, wv = tid >> 6;

  // ---- pass 0': pooled sums from k3 partials (no x sweep) ----
  rs[tid] = rs_g[(size_t)bg*1024 + tid];
  {
    const float* cp = csp_g + (size_t)bg*8192;
    float csum = 0.f;
#pragma unroll
    for (int ss = 0; ss < 8; ++ss) csum += cp[ss*1024 + tid];
    cs[tid] = csum;
  }
  __syncthreads();
  // y = relu(w1 @ [rowmean|colmean] + b1)
  for (int ol = tid; ol < 2048; ol += 1024){
    int o = ol >> 7, l = ol & 127;
    float acc = b1[o];
#pragma unroll
    for (int i = 0; i < 16; ++i){
      float mv = (l < 64 ? rs[i*64 + l] : cs[i*64 + (l-64)]) * (1.f/64.f);
      acc = fmaf(w1[o*16 + i], mv, acc);
    }
    ym[o*128 + l] = fmaxf(acc, 0.f);
  }
  __syncthreads();
  for (int ol = tid; ol < 2048; ol += 1024){
    int q = ol >> 10;             // 0 -> a_h, 1 -> a_w
    int o = (ol >> 6) & 15;
    int p = ol & 63;
    const float* Wm = q ? ww : wh;
    float acc = q ? bw[o] : bh[o];
#pragma unroll
    for (int i = 0; i < 16; ++i)
      acc = fmaf(Wm[o*16 + i], ym[i*128 + q*64 + p], acc);
    float sg = 1.f / (1.f + __expf(-acc));
    (q ? aws : ahs)[o*64 + p] = sg;
  }
  __syncthreads();

  // ---- pass A: mu/var + per-channel sums ----
  const float4* aws4 = (const float4*)aws;
  float s1 = 0.f, s2 = 0.f;
#pragma unroll 4
  for (int k = 0; k < 16; ++k){
    float4 v = x4[k*1024 + tid];
    float ah = ahs[k*64 + h];
    float4 aw = aws4[k*16 + w4];
    float4 x1;
    x1.x = v.x * ah * aw.x;
    x1.y = v.y * ah * aw.y;
    x1.z = v.z * ah * aw.z;
    x1.w = v.w * ah * aw.w;
    float csum = x1.x + x1.y + x1.z + x1.w;
    s1 += csum;
    s2 = fmaf(x1.x, x1.x, s2); s2 = fmaf(x1.y, x1.y, s2);
    s2 = fmaf(x1.z, x1.z, s2); s2 = fmaf(x1.w, x1.w, s2);
    float cw = wred(csum);
    if (lane == 0) chpart[k*16 + wv] = cw;
  }
  float r1 = wred(s1), r2 = wred(s2);
  if (lane == 0){ red1[wv] = r1; red2[wv] = r2; }
  __syncthreads();
  if (tid == 0){
    float S = 0.f, SS = 0.f;
#pragma unroll
    for (int i = 0; i < 16; ++i){ S += red1[i]; SS += red2[i]; }
    float mu = S * (1.f/65536.f);
    float var = SS * (1.f/65536.f) - mu*mu;
    murs[0] = mu; murs[1] = rsqrtf(var + 1e-5f);
  }
  __syncthreads();
  if (tid < 16){
    float ch = 0.f;
#pragma unroll
    for (int m = 0; m < 16; ++m) ch += chpart[tid*16 + m];
    float mu = murs[0], rstd = murs[1];
    float g = gnw[tid], b = gnb[tid];
    float sc = rstd * g;
    sc_s[tid] = sc; of_s[tid] = b - mu*sc;
    v2_s[tid] = (ch * (1.f/4096.f) - mu) * sc + b;   // V2
  }
  __syncthreads();

  // ---- pass B: Z2 per channel; keep exp(x2) bf16-packed in regs ----
  unsigned e2a[16], e2b[16];
#pragma unroll 2
  for (int k = 0; k < 16; ++k){
    float4 v = x4[k*1024 + tid];
    float ah = ahs[k*64 + h];
    float4 aw = aws4[k*16 + w4];
    float sc = sc_s[k], of = of_s[k];
    float ex = __expf(fmaf(v.x * ah * aw.x, sc, of));
    float ey = __expf(fmaf(v.y * ah * aw.y, sc, of));
    float ez = __expf(fmaf(v.z * ah * aw.z, sc, of));
    float ew = __expf(fmaf(v.w * ah * aw.w, sc, of));
    float z = ex + ey + ez + ew;
    e2a[k] = (unsigned)f2b(ex) | ((unsigned)f2b(ey) << 16);
    e2b[k] = (unsigned)f2b(ez) | ((unsigned)f2b(ew) << 16);
    float zw = wred(z);
    if (lane == 0) zpart[k*16 + wv] = zw;
  }
  __syncthreads();
  if (tid < 16){
    float z2 = 0.f;
#pragma unroll
    for (int m = 0; m < 16; ++m) z2 += zpart[tid*16 + m];
    float v3 = 0.f, z3 = 0.f;
#pragma unroll
    for (int ss = 0; ss < 8; ++ss){
      v3 += V3part[((size_t)bg*8 + ss)*16 + tid];
      z3 += Z3part[((size_t)bg*8 + ss)*16 + tid];
    }
    p2s[tid] = v3 * (1.f/4096.f) / z2;   // multiplies exp(x2):  V3 * A2
    p3s[tid] = v2_s[tid] / z3;           // multiplies exp(x3):  V2 * A3
  }
  __syncthreads();

  // ---- pass C: t from register exp(x2) + global E3 (no x re-read) ----
  float4 tacc = make_float4(0.f,0.f,0.f,0.f);
#pragma unroll 4
  for (int k = 0; k < 16; ++k){
    ushort4 eu = E34[k*1024 + tid];
    float p2 = p2s[k], p3 = p3s[k];
    tacc.x += bf2f((unsigned short)(e2a[k] & 0xffffu))*p2 + bf2f(eu.x)*p3;
    tacc.y += bf2f((unsigned short)(e2a[k] >> 16))   *p2 + bf2f(eu.y)*p3;
    tacc.z += bf2f((unsigned short)(e2b[k] & 0xffffu))*p2 + bf2f(eu.z)*p3;
    tacc.w += bf2f((unsigned short)(e2b[k] >> 16))   *p2 + bf2f(eu.w)*p3;
  }
  float4 e;
  e.x = __expf(tacc.x); e.y = __expf(tacc.y);
  e.z = __expf(tacc.z); e.w = __expf(tacc.w);
  float es = e.x + e.y + e.z + e.w;
  float rr = wred(es);
  if (lane == 0) red1[wv] = rr;
  __syncthreads();
  if (tid == 0){
    float S = 0.f;
#pragma unroll
    for (int i = 0; i < 16; ++i) S += red1[i];
    invS_s = 1.f / S;
  }
  __syncthreads();
  float iS = invS_s;
  float4 ei = make_float4(e.x*iS, e.y*iS, e.z*iS, e.w*iS);

  // ---- pass D: out = x * s ----
#pragma unroll 4
  for (int k = 0; k < 16; ++k){
    float4 v = x4[k*1024 + tid];
    float4 ov;
    ov.x = v.x * ei.x; ov.y = v.y * ei.y;
    ov.z = v.z * ei.z; ov.w = v.w * ei.w;
    o4[k*1024 + tid] = ov;
  }
}

extern "C" void kernel_launch(void* const* d_in, const int* in_sizes, int n_in,
                              void* d_out, int out_size, void* d_ws, size_t ws_size,
                              hipStream_t stream)
{
  const float* x   = (const float*)d_in[0];
  const float* w1  = (const float*)d_in[1];
  const float* b1  = (const float*)d_in[2];
  const float* wh  = (const float*)d_in[3];
  const float* bh  = (const float*)d_in[4];
  const float* ww  = (const float*)d_in[5];
  const float* bw  = (const float*)d_in[6];
  const float* w3  = (const float*)d_in[7];
  const float* b3  = (const float*)d_in[8];
  const float* gnw = (const float*)d_in[9];
  const float* gnb = (const float*)d_in[10];
  float* out = (float*)d_out;

  float* V3part = (float*)d_ws;                        // 65536 floats
  float* Z3part = V3part + 65536;                      // 65536 floats
  float* rs_g   = Z3part + 65536;                      // 512*16*64   = 524288 floats
  float* csp_g  = rs_g + 524288;                       // 512*8*16*64 = 4194304 floats
  __hip_bfloat16* E3 = (__hip_bfloat16*)(csp_g + 4194304);  // 33554432 bf16 (64 MB)
  (void)ws_size; (void)n_in; (void)in_sizes; (void)out_size;

  k3_conv<<<dim3(8, 512), 256, 0, stream>>>(x, w3, b3, E3, V3part, Z3part,
                                            rs_g, csp_g);
  mega   <<<512, 1024, 0, stream>>>(x, w1, b1, wh, bh, ww, bw, gnw, gnb,
                                    V3part, Z3part, rs_g, csp_g, E3, out);
}